// Round 4
// baseline (295.096 us; speedup 1.0000x reference)
//
#include <hip/hip_runtime.h>

namespace {

constexpr int HW     = 512 * 512;        // 2^18
constexpr int NBATCH = 4;
constexpr int NPIX   = NBATCH * HW;      // 1,048,576
constexpr int NCLS   = 26;
constexpr float EPS  = 1e-8f;

__global__ __launch_bounds__(64) void hiera_zero(float* __restrict__ acc) {
  if (threadIdx.x < 3) acc[threadIdx.x] = 0.0f;
}

// One pixel per thread: ~26 live floats, 26 independent coalesced 4B loads,
// 16384 waves of TLP. (4-px/thread variant needed 104+ live VGPRs -> compiler
// serialized load/compute rounds -> latency-bound at 138 us.)
__global__ __launch_bounds__(256) void hiera_main(
    const float* __restrict__ logits, const int* __restrict__ labels,
    float* __restrict__ acc) {
  constexpr int LP[20] = {0,0,0,1,1,1,2,2,2,3,3,3,4,4,4,5,5,5,5,5};

  const int p  = blockIdx.x * blockDim.x + threadIdx.x;   // grid covers NPIX exactly
  const int b  = p >> 18;                                  // p / HW
  const int hw = p & (HW - 1);                             // p % HW
  const float* base = logits + ((size_t)b * NCLS << 18) + hw;

  // Load 26 channel logits for this pixel (stride HW -> fully coalesced per wave),
  // apply sigmoid via hardware exp + rcp.
  float pr[NCLS];
#pragma unroll
  for (int c = 0; c < NCLS; ++c) {
    const float x = base[(size_t)c << 18];
    pr[c] = __builtin_amdgcn_rcpf(1.0f + __expf(-x));
  }
  const int L = labels[p];
  const bool valid = (L != 26);

  // ---- leaf set (k = 20) ----
  float cmax[6] = {0.f, 0.f, 0.f, 0.f, 0.f, 0.f};   // probs > 0, so 0-init ok
  float bce_l = 0.0f, se_l = 0.0f, sel_l = 0.0f;
  int parL = -1;
#pragma unroll
  for (int i = 0; i < 20; ++i) {
    const int lp = LP[i];
    const float m  = pr[6 + i];                 // mcma_leaf
    const float mc = fminf(m, pr[lp]);          // mcla_leaf
    cmax[lp] = fmaxf(cmax[lp], m);
    const bool lab = (L == 6 + i);
    bce_l -= __logf(lab ? (mc + EPS) : (1.0f - m + EPS));
    se_l  += __expf(m);                         // m in (0,1): no max-shift needed
    sel_l  = lab ? m : sel_l;
    parL   = lab ? lp : parL;
  }
  const float lse_l = __logf(se_l);

  // ---- parent set (k = 6) ----
  float bce_p = 0.0f, se_p = 0.0f, sel_p = 0.0f;
#pragma unroll
  for (int q = 0; q < 6; ++q) {
    const float mm = fmaxf(pr[q], cmax[q]);     // mcma_par
    const bool lab = (L == q) || (parL == q);   // exactly one true when valid
    bce_p -= __logf(lab ? (pr[q] + EPS) : (1.0f - mm + EPS));
    se_p  += __expf(mm);
    sel_p  = lab ? mm : sel_p;
  }
  const float lse_p = __logf(se_p);

  float a_bce = 0.0f, a_ce = 0.0f, a_vd = 0.0f;
  if (valid) {
    a_vd  = 1.0f;
    a_bce = bce_l * (1.0f / 20.0f) + bce_p * (1.0f / 6.0f);
    a_ce  = lse_p - sel_p;                      // parent CE (one-hot label)
    if (L >= 6) a_ce += lse_l - sel_l;          // leaf CE only if label is a leaf
  }
  // invalid pixels: all BCE terms 0; CE numerator 0, still counted in the
  // CE mean denominator (divide by NPIX in finalize).

  // ---- block reduction: wave shuffle -> LDS -> atomics ----
  const int lane = threadIdx.x & 63;
  const int wid  = threadIdx.x >> 6;
#pragma unroll
  for (int off = 32; off > 0; off >>= 1) {
    a_bce += __shfl_down(a_bce, off);
    a_ce  += __shfl_down(a_ce,  off);
    a_vd  += __shfl_down(a_vd,  off);
  }
  __shared__ float sred[3][4];
  if (lane == 0) { sred[0][wid] = a_bce; sred[1][wid] = a_ce; sred[2][wid] = a_vd; }
  __syncthreads();
  if (threadIdx.x == 0) {
    atomicAdd(&acc[0], sred[0][0] + sred[0][1] + sred[0][2] + sred[0][3]);
    atomicAdd(&acc[1], sred[1][0] + sred[1][1] + sred[1][2] + sred[1][3]);
    atomicAdd(&acc[2], sred[2][0] + sred[2][1] + sred[2][2] + sred[2][3]);
  }
}

__global__ __launch_bounds__(64) void hiera_final(const float* __restrict__ acc,
                                                  float* __restrict__ out) {
  if (threadIdx.x == 0) {
    const float loss = acc[0] / acc[2];             // already scaled by 1/20, 1/6
    const float ce   = acc[1] * (1.0f / (float)NPIX);
    out[0] = 5.0f * loss + ce;
  }
}

}  // namespace

extern "C" void kernel_launch(void* const* d_in, const int* in_sizes, int n_in,
                              void* d_out, int out_size, void* d_ws, size_t ws_size,
                              hipStream_t stream) {
  const float* logits = (const float*)d_in[0];
  const int*   labels = (const int*)d_in[1];
  float* acc = (float*)d_ws;   // 3 floats
  float* out = (float*)d_out;

  hiera_zero<<<1, 64, 0, stream>>>(acc);
  hiera_main<<<NPIX / 256, 256, 0, stream>>>(logits, labels, acc);  // 4096 blocks
  hiera_final<<<1, 64, 0, stream>>>(acc, out);
}

// Round 5
// 217.824 us; speedup vs baseline: 1.3547x; 1.3547x over previous
//
#include <hip/hip_runtime.h>

namespace {

constexpr int HW     = 512 * 512;        // 2^18
constexpr int NBATCH = 4;
constexpr int NPIX   = NBATCH * HW;      // 1,048,576
constexpr int NCLS   = 26;
constexpr int TILE   = 512;              // pixels per block
constexpr float EPS  = 1e-8f;

__global__ __launch_bounds__(64) void hiera_zero(float* __restrict__ acc) {
  if (threadIdx.x < 3) acc[threadIdx.x] = 0.0f;
}

// Per-pixel loss math (verified bit-exact vs reference in R3/R4: absmax 0.0).
__device__ __forceinline__ void pixel_loss(const float pr[NCLS], const int L,
                                           float& a_bce, float& a_ce, float& a_vd) {
  constexpr int LP[20] = {0,0,0,1,1,1,2,2,2,3,3,3,4,4,4,5,5,5,5,5};
  const bool valid = (L != 26);

  // ---- leaf set (k = 20) ----
  float cmax[6] = {0.f, 0.f, 0.f, 0.f, 0.f, 0.f};
  float bce_l = 0.0f, se_l = 0.0f, sel_l = 0.0f;
  int parL = -1;
#pragma unroll
  for (int i = 0; i < 20; ++i) {
    const int lp = LP[i];
    const float m  = pr[6 + i];                 // mcma_leaf
    const float mc = fminf(m, pr[lp]);          // mcla_leaf
    cmax[lp] = fmaxf(cmax[lp], m);
    const bool lab = (L == 6 + i);
    bce_l -= __logf(lab ? (mc + EPS) : (1.0f - m + EPS));
    se_l  += __expf(m);                         // m in (0,1): no max-shift needed
    sel_l  = lab ? m : sel_l;
    parL   = lab ? lp : parL;
  }
  const float lse_l = __logf(se_l);

  // ---- parent set (k = 6) ----
  float bce_p = 0.0f, se_p = 0.0f, sel_p = 0.0f;
#pragma unroll
  for (int q = 0; q < 6; ++q) {
    const float mm = fmaxf(pr[q], cmax[q]);     // mcma_par
    const bool lab = (L == q) || (parL == q);   // exactly one true when valid
    bce_p -= __logf(lab ? (pr[q] + EPS) : (1.0f - mm + EPS));
    se_p  += __expf(mm);
    sel_p  = lab ? mm : sel_p;
  }
  const float lse_p = __logf(se_p);

  if (valid) {
    a_vd  += 1.0f;
    a_bce += bce_l * (1.0f / 20.0f) + bce_p * (1.0f / 6.0f);
    a_ce  += lse_p - sel_p;                     // parent CE (one-hot label)
    if (L >= 6) a_ce += lse_l - sel_l;          // leaf CE only if label is a leaf
  }
}

// LDS-staged: global_load_lds has no dest regs -> all 13 chunk-loads per wave
// stay in flight by construction (R3/R4 showed the compiler serializes
// register-destined strided loads: VGPR=20, rematerialized chains, 186us).
__global__ __launch_bounds__(256) void hiera_main(
    const float* __restrict__ logits, const int* __restrict__ labels,
    float* __restrict__ acc) {
  __shared__ float tile[NCLS][TILE];            // 52 KB -> 3 blocks/CU

  const int b    = blockIdx.x >> 9;             // HW/TILE = 512 tiles per image
  const int thw  = (blockIdx.x & 511) * TILE;   // tile base pixel within image
  const int w    = threadIdx.x >> 6;            // wave 0..3
  const int lane = threadIdx.x & 63;
  const float* gbase = logits + (size_t)b * NCLS * HW + thw;

  // Stage 26 channels x 512 px = 52 KB as 52 chunks of 1 KB (64 lanes x 16 B).
#pragma unroll
  for (int i = 0; i < 13; ++i) {
    const int j    = i * 4 + w;                 // chunk 0..51 (wave-uniform)
    const int c    = j >> 1;
    const int half = (j & 1) * 256;
    const float* g = gbase + (size_t)c * HW + half + lane * 4;
    float* l = &tile[c][half];                  // uniform base; HW adds lane*16B
    __builtin_amdgcn_global_load_lds(
        (const __attribute__((address_space(1))) void*)g,
        (__attribute__((address_space(3))) void*)l, 16, 0, 0);
  }
  __syncthreads();                              // drains vmcnt before LDS reads

  // Each thread: 2 adjacent pixels. float2 LDS reads, conflict-free.
  const int t = threadIdx.x;
  float2 p2[NCLS];
#pragma unroll
  for (int c = 0; c < NCLS; ++c)
    p2[c] = *reinterpret_cast<const float2*>(&tile[c][2 * t]);
  const int2 lb = *reinterpret_cast<const int2*>(&labels[(size_t)b * HW + thw + 2 * t]);

  float a_bce = 0.0f, a_ce = 0.0f, a_vd = 0.0f;
  {
    float pr[NCLS];
#pragma unroll
    for (int c = 0; c < NCLS; ++c)
      pr[c] = __builtin_amdgcn_rcpf(1.0f + __expf(-p2[c].x));
    pixel_loss(pr, lb.x, a_bce, a_ce, a_vd);
  }
  {
    float pr[NCLS];
#pragma unroll
    for (int c = 0; c < NCLS; ++c)
      pr[c] = __builtin_amdgcn_rcpf(1.0f + __expf(-p2[c].y));
    pixel_loss(pr, lb.y, a_bce, a_ce, a_vd);
  }

  // ---- block reduction: wave shuffle -> LDS -> atomics ----
#pragma unroll
  for (int off = 32; off > 0; off >>= 1) {
    a_bce += __shfl_down(a_bce, off);
    a_ce  += __shfl_down(a_ce,  off);
    a_vd  += __shfl_down(a_vd,  off);
  }
  __shared__ float sred[3][4];
  if (lane == 0) { sred[0][w] = a_bce; sred[1][w] = a_ce; sred[2][w] = a_vd; }
  __syncthreads();
  if (threadIdx.x == 0) {
    atomicAdd(&acc[0], sred[0][0] + sred[0][1] + sred[0][2] + sred[0][3]);
    atomicAdd(&acc[1], sred[1][0] + sred[1][1] + sred[1][2] + sred[1][3]);
    atomicAdd(&acc[2], sred[2][0] + sred[2][1] + sred[2][2] + sred[2][3]);
  }
}

__global__ __launch_bounds__(64) void hiera_final(const float* __restrict__ acc,
                                                  float* __restrict__ out) {
  if (threadIdx.x == 0) {
    const float loss = acc[0] / acc[2];             // already scaled by 1/20, 1/6
    const float ce   = acc[1] * (1.0f / (float)NPIX);
    out[0] = 5.0f * loss + ce;
  }
}

}  // namespace

extern "C" void kernel_launch(void* const* d_in, const int* in_sizes, int n_in,
                              void* d_out, int out_size, void* d_ws, size_t ws_size,
                              hipStream_t stream) {
  const float* logits = (const float*)d_in[0];
  const int*   labels = (const int*)d_in[1];
  float* acc = (float*)d_ws;   // 3 floats
  float* out = (float*)d_out;

  hiera_zero<<<1, 64, 0, stream>>>(acc);
  hiera_main<<<NPIX / TILE, 256, 0, stream>>>(logits, labels, acc);  // 2048 blocks
  hiera_final<<<1, 64, 0, stream>>>(acc, out);
}

// Round 7
// 188.570 us; speedup vs baseline: 1.5649x; 1.1551x over previous
//
#include <hip/hip_runtime.h>

namespace {

constexpr int HW     = 512 * 512;        // 2^18
constexpr int NBATCH = 4;
constexpr int NPIX   = NBATCH * HW;      // 1,048,576
constexpr int NCLS   = 26;
constexpr int TILE   = 256;              // pixels per tile
constexpr int NTILES = NPIX / TILE;      // 4096
constexpr int GRID   = 768;              // 3 blocks/CU resident (LDS-capped)
constexpr float EPS  = 1e-8f;

__global__ __launch_bounds__(64) void hiera_zero(float* __restrict__ acc) {
  if (threadIdx.x < 3) acc[threadIdx.x] = 0.0f;
}

// Per-pixel loss math (bit-exact vs reference: absmax 0.0 in R3/R4/R5).
__device__ __forceinline__ void pixel_loss(const float pr[NCLS], const int L,
                                           float& a_bce, float& a_ce, float& a_vd) {
  constexpr int LP[20] = {0,0,0,1,1,1,2,2,2,3,3,3,4,4,4,5,5,5,5,5};
  const bool valid = (L != 26);

  float cmax[6] = {0.f, 0.f, 0.f, 0.f, 0.f, 0.f};
  float bce_l = 0.0f, se_l = 0.0f, sel_l = 0.0f;
  int parL = -1;
#pragma unroll
  for (int i = 0; i < 20; ++i) {
    const int lp = LP[i];
    const float m  = pr[6 + i];                 // mcma_leaf
    const float mc = fminf(m, pr[lp]);          // mcla_leaf
    cmax[lp] = fmaxf(cmax[lp], m);
    const bool lab = (L == 6 + i);
    bce_l -= __logf(lab ? (mc + EPS) : (1.0f - m + EPS));
    se_l  += __expf(m);                         // m in (0,1): no max-shift needed
    sel_l  = lab ? m : sel_l;
    parL   = lab ? lp : parL;
  }
  const float lse_l = __logf(se_l);

  float bce_p = 0.0f, se_p = 0.0f, sel_p = 0.0f;
#pragma unroll
  for (int q = 0; q < 6; ++q) {
    const float mm = fmaxf(pr[q], cmax[q]);     // mcma_par
    const bool lab = (L == q) || (parL == q);   // exactly one true when valid
    bce_p -= __logf(lab ? (pr[q] + EPS) : (1.0f - mm + EPS));
    se_p  += __expf(mm);
    sel_p  = lab ? mm : sel_p;
  }
  const float lse_p = __logf(se_p);

  if (valid) {
    a_vd  += 1.0f;
    a_bce += bce_l * (1.0f / 20.0f) + bce_p * (1.0f / 6.0f);
    a_ce  += lse_p - sel_p;                     // parent CE (one-hot label)
    if (L >= 6) a_ce += lse_l - sel_l;          // leaf CE only if label is a leaf
  }
}

// Persistent blocks, double-buffered global_load_lds pipeline:
// stage(t+GRID) issued BEFORE compute(t); __syncthreads()'s vmcnt(0) drain
// lands after a full compute phase, so DMA latency is hidden (R5 exposed it:
// stage -> barrier -> compute -> exit per short-lived block = 101us).
__global__ __launch_bounds__(256) void hiera_main(
    const float* __restrict__ logits, const int* __restrict__ labels,
    float* __restrict__ acc) {
  __shared__ float buf[2][NCLS][TILE];          // 2 x 26 KB = 53248 B
  __shared__ float sred[3][4];

  const int w    = threadIdx.x >> 6;            // wave 0..3
  const int lane = threadIdx.x & 63;
  const int t    = threadIdx.x;

  // Stage one tile (26 channels x 256 px = 26 KB) as 26 chunks of 1 KB.
  auto stage = [&](int tile, int which) {
    const int b   = tile >> 10;                 // 1024 tiles per image
    const int hw0 = (tile & 1023) * TILE;
    const float* g0 = logits + ((size_t)b * NCLS << 18) + hw0 + lane * 4;
    for (int c = w; c < NCLS; c += 4) {         // wave-uniform bound (7/7/6/6)
      __builtin_amdgcn_global_load_lds(
          (const __attribute__((address_space(1))) void*)(g0 + ((size_t)c << 18)),
          (__attribute__((address_space(3))) void*)&buf[which][c][0], 16, 0, 0);
    }
  };

  float a_bce = 0.0f, a_ce = 0.0f, a_vd = 0.0f;
  int cur = 0;

  stage(blockIdx.x, 0);                         // prologue (latency exposed once)
  __syncthreads();

  for (int tile = blockIdx.x; tile < NTILES; tile += GRID) {
    const int nxt = tile + GRID;
    if (nxt < NTILES) stage(nxt, cur ^ 1);      // prefetch next tile
    __builtin_amdgcn_sched_barrier(0);          // pin: DMA issued before compute

    const int b   = tile >> 10;
    const int hw0 = (tile & 1023) * TILE;
    const int L   = labels[((size_t)b << 18) + hw0 + t];
    float pr[NCLS];
#pragma unroll
    for (int c = 0; c < NCLS; ++c)              // ds_read_b32, conflict-free
      pr[c] = __builtin_amdgcn_rcpf(1.0f + __expf(-buf[cur][c][t]));
    pixel_loss(pr, L, a_bce, a_ce, a_vd);

    __syncthreads();   // vmcnt(0): next buffer ready; all reads of cur done
    cur ^= 1;
  }

  // ---- block reduction: wave shuffle -> LDS -> atomics (once per block) ----
#pragma unroll
  for (int off = 32; off > 0; off >>= 1) {
    a_bce += __shfl_down(a_bce, off);
    a_ce  += __shfl_down(a_ce,  off);
    a_vd  += __shfl_down(a_vd,  off);
  }
  if (lane == 0) { sred[0][w] = a_bce; sred[1][w] = a_ce; sred[2][w] = a_vd; }
  __syncthreads();
  if (threadIdx.x == 0) {
    atomicAdd(&acc[0], sred[0][0] + sred[0][1] + sred[0][2] + sred[0][3]);
    atomicAdd(&acc[1], sred[1][0] + sred[1][1] + sred[1][2] + sred[1][3]);
    atomicAdd(&acc[2], sred[2][0] + sred[2][1] + sred[2][2] + sred[2][3]);
  }
}

__global__ __launch_bounds__(64) void hiera_final(const float* __restrict__ acc,
                                                  float* __restrict__ out) {
  if (threadIdx.x == 0) {
    const float loss = acc[0] / acc[2];             // already scaled by 1/20, 1/6
    const float ce   = acc[1] * (1.0f / (float)NPIX);
    out[0] = 5.0f * loss + ce;
  }
}

}  // namespace

extern "C" void kernel_launch(void* const* d_in, const int* in_sizes, int n_in,
                              void* d_out, int out_size, void* d_ws, size_t ws_size,
                              hipStream_t stream) {
  const float* logits = (const float*)d_in[0];
  const int*   labels = (const int*)d_in[1];
  float* acc = (float*)d_ws;   // 3 floats
  float* out = (float*)d_out;

  hiera_zero<<<1, 64, 0, stream>>>(acc);
  hiera_main<<<GRID, 256, 0, stream>>>(logits, labels, acc);
  hiera_final<<<1, 64, 0, stream>>>(acc, out);
}